// Round 2
// baseline (1841.718 us; speedup 1.0000x reference)
//
#include <hip/hip_runtime.h>

// Batched complex QR (Householder, LAPACK clarfg/cgeqr2/cung2r convention).
// One batch element per wave; lane = matrix row (M=64 == wavefront size).
// Factorization runs in FP64 internally so that the sign decision
// sign(Re(alpha_i)) matches a float64 reference on near-tie columns
// (fp32 accumulation error ~4e-5 across 524288 sign decisions gives O(1)
// expected phase flips -> absmax ~0.8, which is what round 1 showed).
// Q formation (cung2r) runs in FP32: signs are locked by then and value
// error ~1e-6 is far under the 1e-2 threshold.

constexpr int Mrows = 64;
constexpr int Rcols = 16;

__device__ __forceinline__ double wsum64d(double v) {
#pragma unroll
  for (int m = 32; m >= 1; m >>= 1) v += __shfl_xor(v, m, 64);
  return v;
}

__device__ __forceinline__ float wsum64f(float v) {
#pragma unroll
  for (int m = 32; m >= 1; m >>= 1) v += __shfl_xor(v, m, 64);
  return v;
}

__global__ __launch_bounds__(256) void qr_house_kernel(
    const float* __restrict__ x, float* __restrict__ out, int B) {
  const int lane = threadIdx.x & 63;
  const int wave = threadIdx.x >> 6;
  const int b = blockIdx.x * 4 + wave;
  if (b >= B) return;

  // Load row `lane` of batch b: 16 complex = 8 float4, contiguous per lane.
  const float4* xp = reinterpret_cast<const float4*>(
      x + (size_t)b * (Mrows * Rcols * 2) + (size_t)lane * (Rcols * 2));
  double ar[Rcols], ai[Rcols];
#pragma unroll
  for (int k = 0; k < Rcols / 2; ++k) {
    float4 t = xp[k];
    ar[2 * k] = (double)t.x;
    ai[2 * k] = (double)t.y;
    ar[2 * k + 1] = (double)t.z;
    ai[2 * k + 1] = (double)t.w;
  }

  double taur[Rcols], taui[Rcols];

  // ---- Factorization: cgeqr2 in fp64 (apply H_i^H = I - conj(tau) v v^H) ----
#pragma unroll
  for (int i = 0; i < Rcols; ++i) {
    // clarfg on column i, rows i..M-1. alpha = A[i][i], x = A[i+1..][i].
    double cr = ar[i], ci = ai[i];
    double sq = (lane > i) ? (cr * cr + ci * ci) : 0.0;
    double xnorm2 = wsum64d(sq);
    double alphr = __shfl(cr, i, 64);
    double alphi = __shfl(ci, i, 64);

    double tr, ti;
    if (xnorm2 == 0.0 && alphi == 0.0) {
      tr = 0.0;
      ti = 0.0;
    } else {
      double nrm = sqrt(alphr * alphr + alphi * alphi + xnorm2);
      double beta = (alphr >= 0.0) ? -nrm : nrm;  // -SIGN(nrm, alphr)
      double rb = 1.0 / beta;
      tr = (beta - alphr) * rb;
      ti = -alphi * rb;
      // v = x / (alpha - beta), stored in-place below the diagonal.
      double dr = alphr - beta, di = alphi;
      double inv = 1.0 / (dr * dr + di * di);
      double sr = dr * inv, si = -di * inv;
      if (lane > i) {
        double nr = cr * sr - ci * si;
        double ni = cr * si + ci * sr;
        ar[i] = nr;
        ai[i] = ni;
      }
    }
    taur[i] = tr;
    taui[i] = ti;

    // v: v[i]=1, v[m>i]=stored, v[m<i]=0
    double vr = (lane == i) ? 1.0 : ((lane > i) ? ar[i] : 0.0);
    double vi = (lane == i) ? 0.0 : ((lane > i) ? ai[i] : 0.0);
    const double ctr = tr, cti = -ti;  // conj(tau)
#pragma unroll
    for (int j = i + 1; j < Rcols; ++j) {
      // dot = v^H a_j
      double pr = vr * ar[j] + vi * ai[j];
      double pi = vr * ai[j] - vi * ar[j];
      pr = wsum64d(pr);
      pi = wsum64d(pi);
      double wr = ctr * pr - cti * pi;
      double wi = ctr * pi + cti * pr;
      ar[j] -= wr * vr - wi * vi;
      ai[j] -= wr * vi + wi * vr;
    }
  }

  // ---- Round reflectors + taus to fp32 for Q formation ----
  float vfr[Rcols], vfi[Rcols], tfr[Rcols], tfi[Rcols];
#pragma unroll
  for (int i = 0; i < Rcols; ++i) {
    vfr[i] = (lane == i) ? 1.0f : ((lane > i) ? (float)ar[i] : 0.0f);
    vfi[i] = (lane == i) ? 0.0f : ((lane > i) ? (float)ai[i] : 0.0f);
    tfr[i] = (float)taur[i];
    tfi[i] = (float)taui[i];
  }

  // ---- Q formation: cung2r in fp32 (apply H_i = I - tau v v^H, i = R-1..0) ----
  float qre[Rcols], qim[Rcols];
#pragma unroll
  for (int i = Rcols - 1; i >= 0; --i) {
    const float tr = tfr[i], ti = tfi[i];
    const float vr = vfr[i], vi = vfi[i];
#pragma unroll
    for (int j = i + 1; j < Rcols; ++j) {
      float pr = vr * qre[j] + vi * qim[j];
      float pi = vr * qim[j] - vi * qre[j];
      pr = wsum64f(pr);
      pi = wsum64f(pi);
      // w = tau * dot (NOT conjugated in cung2r)
      float wr = tr * pr - ti * pi;
      float wi = tr * pi + ti * pr;
      qre[j] -= wr * vr - wi * vi;
      qim[j] -= wr * vi + wi * vr;
    }
    // Column i: lane i -> 1 - tau; lanes > i -> -tau * v; lanes < i -> 0.
    float dr = -(tr * vr - ti * vi);
    float di = -(tr * vi + ti * vr);
    if (lane == i) {
      dr = 1.0f - tr;
      di = -ti;
    }
    if (lane < i) {
      dr = 0.0f;
      di = 0.0f;
    }
    qre[i] = dr;
    qim[i] = di;
  }

  // Store Q row: interleave (re, im) pairs, 8 float4 per lane.
  float4* op = reinterpret_cast<float4*>(
      out + (size_t)b * (Mrows * Rcols * 2) + (size_t)lane * (Rcols * 2));
#pragma unroll
  for (int k = 0; k < Rcols / 2; ++k) {
    op[k] = make_float4(qre[2 * k], qim[2 * k], qre[2 * k + 1], qim[2 * k + 1]);
  }
}

extern "C" void kernel_launch(void* const* d_in, const int* in_sizes, int n_in,
                              void* d_out, int out_size, void* d_ws,
                              size_t ws_size, hipStream_t stream) {
  const float* x = (const float*)d_in[0];
  float* out = (float*)d_out;
  const int B = in_sizes[0] / (Mrows * Rcols * 2);
  dim3 block(256);  // 4 waves -> 4 batch elements per block
  dim3 grid((B + 3) / 4);
  qr_house_kernel<<<grid, block, 0, stream>>>(x, out, B);
}